// Round 1
// baseline (247.777 us; speedup 1.0000x reference)
//
#include <hip/hip_runtime.h>
#include <math.h>

#define BB 16
#define TT 128
#define II 8
#define DD 128

// out layout: embeddings (T,B,D) [262144] | padding_mask (B,T) [2048]
//             | sequence_mask (T,B,1) [2048] | global_mask (T) [128]

__device__ __forceinline__ float gelu_f(float x) {
    float x3 = x * x * x;
    return 0.5f * x * (1.0f + tanhf(0.7978845608028654f * (x + 0.044715f * x3)));
}

__device__ __forceinline__ float wave_reduce_sum(float v) {
    for (int o = 32; o >= 1; o >>= 1) v += __shfl_xor(v, o, 64);
    return v;
}
__device__ __forceinline__ float wave_reduce_max(float v) {
    for (int o = 32; o >= 1; o >>= 1) v = fmaxf(v, __shfl_xor(v, o, 64));
    return v;
}

// M[a][e] = sum_d Wq[a][d] * Wk[e][d]   (so kq = x_diag @ M)
__global__ void k0_compute_M(const float* __restrict__ Wq,
                             const float* __restrict__ Wk,
                             float* __restrict__ M) {
    int a = blockIdx.x, e = threadIdx.x;
    float acc = 0.0f;
    for (int d = 0; d < DD; d++) acc += Wq[a * DD + d] * Wk[e * DD + d];
    M[a * DD + e] = acc;
}

// per (r,b): x_diag = LN1(gelu(vec8 @ We + be) * m); kq = x_diag @ M
__global__ void k1_compute_kq(const float* __restrict__ vectors,
                              const int* __restrict__ mask,
                              const float* __restrict__ We,
                              const float* __restrict__ be,
                              const float* __restrict__ g1,
                              const float* __restrict__ b1,
                              const float* __restrict__ Mm,
                              float* __restrict__ kq) {
    int rb = blockIdx.x;              // rb = r*B + b
    int r = rb >> 4, b = rb & 15;
    int d = threadIdx.x;              // 128 threads
    __shared__ float red[DD];
    __shared__ float xs[DD];

    long base = (((long)b * TT + r) * TT + r) * II;
    float e = be[d];
    for (int i = 0; i < II; i++) e += vectors[base + i] * We[i * DD + d];
    float mf = mask[b * TT * TT + r * TT + r] ? 1.0f : 0.0f;
    float g = gelu_f(e) * mf;

    red[d] = g; __syncthreads();
    for (int s = 64; s >= 1; s >>= 1) { if (d < s) red[d] += red[d + s]; __syncthreads(); }
    float mu = red[0] * (1.0f / 128.0f);
    __syncthreads();
    float t = g - mu;
    red[d] = t * t; __syncthreads();
    for (int s = 64; s >= 1; s >>= 1) { if (d < s) red[d] += red[d + s]; __syncthreads(); }
    float var = red[0] * (1.0f / 128.0f);
    float rstd = rsqrtf(var + 1e-5f);
    float x = t * rstd * g1[d] + b1[d];
    xs[d] = x; __syncthreads();

    float acc = 0.0f;
    for (int a2 = 0; a2 < DD; a2++) acc += xs[a2] * Mm[a2 * DD + d];
    kq[rb * DD + d] = acc;
}

// per (r,b): recompute x rows, logits = x·kq, softmax, s = Σ w_c x_c,
// emb = s@Wv, h = gelu(emb@Wo + bo), out = LN2(h+emb)*seq
__global__ __launch_bounds__(256)
void k2_attention(const float* __restrict__ vectors,
                  const int* __restrict__ mask,
                  const float* __restrict__ We,
                  const float* __restrict__ be,
                  const float* __restrict__ g1,
                  const float* __restrict__ b1,
                  const float* __restrict__ Wv,
                  const float* __restrict__ Wo,
                  const float* __restrict__ bo,
                  const float* __restrict__ g2,
                  const float* __restrict__ b2,
                  const float* __restrict__ kq,
                  float* __restrict__ out) {
    __shared__ float xs[TT * DD];      // 64 KB
    __shared__ float logits[TT];
    __shared__ float wgt[TT];
    __shared__ float sp[2 * DD];
    __shared__ float sv[DD];
    __shared__ float ep[2 * DD];
    __shared__ float embL[DD];
    __shared__ float hp[2 * DD];
    __shared__ float red[DD];

    int rb = blockIdx.x;
    int r = rb >> 4, b = rb & 15;
    int t = threadIdx.x;               // 256 threads = 4 waves
    int wave = t >> 6, lane = t & 63;
    int d0 = lane, d1 = lane + 64;

    float kq0 = kq[rb * DD + d0], kq1 = kq[rb * DD + d1];
    float we0[II], we1[II];
    for (int i = 0; i < II; i++) { we0[i] = We[i * DD + d0]; we1[i] = We[i * DD + d1]; }
    float be0 = be[d0], be1 = be[d1];
    float g10 = g1[d0], g11 = g1[d1], b10 = b1[d0], b11 = b1[d1];
    const int* mrow = mask + b * TT * TT + r * TT;
    const float* vbase = vectors + (((long)b * TT + r) * TT) * II;

    // phase 1: each wave builds 32 c-rows + logits
    for (int cc = 0; cc < 32; cc++) {
        int c = wave * 32 + cc;
        float v[II];
        for (int i = 0; i < II; i++) v[i] = vbase[c * II + i];
        float e0 = be0, e1 = be1;
        for (int i = 0; i < II; i++) { e0 += v[i] * we0[i]; e1 += v[i] * we1[i]; }
        int m = mrow[c];
        float mf = m ? 1.0f : 0.0f;
        float a0 = gelu_f(e0) * mf, a1 = gelu_f(e1) * mf;
        float mu = wave_reduce_sum(a0 + a1) * (1.0f / 128.0f);
        float t0 = a0 - mu, t1 = a1 - mu;
        float var = wave_reduce_sum(t0 * t0 + t1 * t1) * (1.0f / 128.0f);
        float rstd = rsqrtf(var + 1e-5f);
        float x0 = t0 * rstd * g10 + b10;
        float x1 = t1 * rstd * g11 + b11;
        xs[c * DD + d0] = x0;
        xs[c * DD + d1] = x1;
        float lp = wave_reduce_sum(x0 * kq0 + x1 * kq1);
        if (lane == 0) {
            float lg = lp * 0.08838834764831845f;   // 1/sqrt(128)
            if (!(m || (c == r))) lg = -1e9f;
            logits[c] = lg;
        }
    }
    __syncthreads();

    // phase 2: softmax over c (wave 0)
    if (wave == 0) {
        float l0 = logits[lane], l1 = logits[lane + 64];
        float mx = wave_reduce_max(fmaxf(l0, l1));
        float e0 = expf(l0 - mx), e1 = expf(l1 - mx);
        float s = wave_reduce_sum(e0 + e1);
        float inv = 1.0f / s;
        wgt[lane] = e0 * inv; wgt[lane + 64] = e1 * inv;
    }
    __syncthreads();

    // phase 3: s[d] = Σ_c w_c * xs[c][d]
    int d = t & 127, half = t >> 7;
    {
        float acc = 0.0f;
        for (int j = 0; j < 64; j++) {
            int c = half * 64 + j;
            acc += wgt[c] * xs[c * DD + d];
        }
        sp[half * DD + d] = acc;
    }
    __syncthreads();
    if (t < DD) sv[t] = sp[t] + sp[DD + t];
    __syncthreads();

    // phase 4a: emb = s @ Wv
    {
        float acc = 0.0f;
        for (int j = 0; j < 64; j++) {
            int e = half * 64 + j;
            acc += sv[e] * Wv[e * DD + d];
        }
        ep[half * DD + d] = acc;
    }
    __syncthreads();
    if (t < DD) embL[t] = ep[t] + ep[DD + t];
    __syncthreads();

    // phase 4b: h = emb @ Wo
    {
        float acc = 0.0f;
        for (int j = 0; j < 64; j++) {
            int e2 = half * 64 + j;
            acc += embL[e2] * Wo[e2 * DD + d];
        }
        hp[half * DD + d] = acc;
    }
    __syncthreads();

    // phase 5: LN2(h + emb) * seq
    float z = 0.0f;
    if (t < DD) {
        float emv = embL[t];
        float h = gelu_f(hp[t] + hp[DD + t] + bo[t]);
        z = h + emv;
        red[t] = z;
    }
    __syncthreads();
    for (int s = 64; s >= 1; s >>= 1) { if (t < s) red[t] += red[t + s]; __syncthreads(); }
    float mu = red[0] * (1.0f / 128.0f);
    __syncthreads();
    float tt2 = z - mu;
    if (t < DD) red[t] = tt2 * tt2;
    __syncthreads();
    for (int s = 64; s >= 1; s >>= 1) { if (t < s) red[t] += red[t + s]; __syncthreads(); }
    float var = red[0] * (1.0f / 128.0f);
    float rstd = rsqrtf(var + 1e-5f);
    if (t < DD) {
        float seqf = mrow[r] ? 1.0f : 0.0f;
        out[rb * DD + t] = (tt2 * rstd * g2[t] + b2[t]) * seqf;
    }
}

// bool-ish tail outputs
__global__ void k3_tail(const int* __restrict__ mask, float* __restrict__ out) {
    int idx = blockIdx.x * 256 + threadIdx.x;
    if (idx < 2048) {                       // padding_mask (B,T) = !real
        int b = idx >> 7, tt = idx & 127;
        out[262144 + idx] = mask[b * TT * TT + tt * TT + tt] ? 0.0f : 1.0f;
    } else if (idx < 4096) {                // sequence_mask (T,B,1) = real
        int i2 = idx - 2048;
        int tt = i2 >> 4, b = i2 & 15;
        out[264192 + i2] = mask[b * TT * TT + tt * TT + tt] ? 1.0f : 0.0f;
    } else if (idx < 4224) {                // global_mask (T) = ones
        out[266240 + (idx - 4096)] = 1.0f;
    }
}

extern "C" void kernel_launch(void* const* d_in, const int* in_sizes, int n_in,
                              void* d_out, int out_size, void* d_ws, size_t ws_size,
                              hipStream_t stream) {
    const float* vectors = (const float*)d_in[0];
    const int*   mask    = (const int*)d_in[1];
    const float* W_embed = (const float*)d_in[2];
    const float* b_embed = (const float*)d_in[3];
    const float* ln1_g   = (const float*)d_in[4];
    const float* ln1_b   = (const float*)d_in[5];
    const float* Wq      = (const float*)d_in[6];
    const float* Wk      = (const float*)d_in[7];
    const float* Wv      = (const float*)d_in[8];
    const float* W_out   = (const float*)d_in[9];
    const float* b_out   = (const float*)d_in[10];
    const float* ln2_g   = (const float*)d_in[11];
    const float* ln2_b   = (const float*)d_in[12];
    float* out = (float*)d_out;

    float* wsf = (float*)d_ws;
    float* M   = wsf;                  // 128*128
    float* kq  = wsf + DD * DD;        // 2048*128

    hipLaunchKernelGGL(k0_compute_M, dim3(DD), dim3(DD), 0, stream, Wq, Wk, M);
    hipLaunchKernelGGL(k1_compute_kq, dim3(TT * BB), dim3(DD), 0, stream,
                       vectors, mask, W_embed, b_embed, ln1_g, ln1_b, M, kq);
    hipLaunchKernelGGL(k2_attention, dim3(TT * BB), dim3(256), 0, stream,
                       vectors, mask, W_embed, b_embed, ln1_g, ln1_b,
                       Wv, W_out, b_out, ln2_g, ln2_b, kq, out);
    hipLaunchKernelGGL(k3_tail, dim3(17), dim3(256), 0, stream, mask, out);
}

// Round 2
// 158.323 us; speedup vs baseline: 1.5650x; 1.5650x over previous
//
#include <hip/hip_runtime.h>
#include <hip/hip_fp16.h>
#include <math.h>

#define BB 16
#define TT 128
#define II 8
#define DD 128

// out layout: embeddings (T,B,D) [262144] | padding_mask (B,T) [2048]
//             | sequence_mask (T,B,1) [2048] | global_mask (T) [128]

// tanh-gelu via hardware exp: tanh(v) = 1 - 2/(e^{2v}+1); handles +-inf safely.
__device__ __forceinline__ float fast_gelu(float x) {
    float u = 1.5957691216057308f * x * (1.0f + 0.044715f * x * x); // 2*0.7978845608*(x+0.044715x^3)
    float e = __expf(u);
    float th = 1.0f - __fdividef(2.0f, e + 1.0f);
    return 0.5f * x * (1.0f + th);
}

// M[a][e] = sum_d Wq[a][d] * Wk[e][d]   (kq = x_diag @ M)
__global__ void k0_compute_M(const float* __restrict__ Wq,
                             const float* __restrict__ Wk,
                             float* __restrict__ M) {
    __shared__ float wq[DD];
    int a = blockIdx.x, e = threadIdx.x;
    wq[e] = Wq[a * DD + e];
    __syncthreads();
    const float4* wk4 = (const float4*)(Wk + e * DD);
    float acc = 0.0f;
    #pragma unroll 8
    for (int d4 = 0; d4 < DD / 4; d4++) {
        float4 w = wk4[d4];
        acc += wq[d4 * 4 + 0] * w.x + wq[d4 * 4 + 1] * w.y +
               wq[d4 * 4 + 2] * w.z + wq[d4 * 4 + 3] * w.w;
    }
    M[a * DD + e] = acc;
}

__global__ __launch_bounds__(256, 4)
void k_fused(const float* __restrict__ vectors,
             const int* __restrict__ mask,
             const float* __restrict__ We,
             const float* __restrict__ be,
             const float* __restrict__ g1,
             const float* __restrict__ b1,
             const float* __restrict__ Wv,
             const float* __restrict__ Wo,
             const float* __restrict__ bo,
             const float* __restrict__ g2,
             const float* __restrict__ b2,
             const float* __restrict__ Mws,
             float* __restrict__ out) {
    __shared__ __half2 xs2[TT * 64];   // 32 KB: x rows, fp16, d-pairs
    __shared__ float2 xr2[64];         // diag row (c==r) fp32
    __shared__ float2 pbuf2[256];      // cross-wave partials
    __shared__ float2 kq2[64];         // kq * 1/sqrt(D)
    __shared__ float  lp[2 * TT];      // logit partials
    __shared__ float  wgt[TT];         // softmax weights
    __shared__ float2 sv2[64];         // s = sum_c w_c x_c
    __shared__ float2 emb2[64];        // emb = s @ Wv

    int rb = blockIdx.x;
    int r = rb >> 4, b = rb & 15;
    int t = threadIdx.x;
    int wave = t >> 6, lane = t & 63;

    const int* mrow = mask + b * TT * TT + r * TT;
    const float4* vb4 = (const float4*)(vectors + (((long)b * TT + r) * TT) * II);

    // per-lane d-pair params (d0=2*lane, d1=2*lane+1)
    float2 we2[II];
    const float2* We2 = (const float2*)We;
    #pragma unroll
    for (int i = 0; i < II; i++) we2[i] = We2[i * 64 + lane];
    float2 be2 = ((const float2*)be)[lane];
    float2 g12 = ((const float2*)g1)[lane];
    float2 b12 = ((const float2*)b1)[lane];

    // ---- phase 1: build 128 x-rows (each wave: 32 rows, 2 at a time for ILP)
    for (int cc = 0; cc < 32; cc += 2) {
        int cA = (wave << 5) + cc, cB = cA + 1;
        float4 vA0 = vb4[cA * 2], vA1 = vb4[cA * 2 + 1];
        float4 vB0 = vb4[cB * 2], vB1 = vb4[cB * 2 + 1];
        float vA[8] = {vA0.x, vA0.y, vA0.z, vA0.w, vA1.x, vA1.y, vA1.z, vA1.w};
        float vB[8] = {vB0.x, vB0.y, vB0.z, vB0.w, vB1.x, vB1.y, vB1.z, vB1.w};
        float eA0 = be2.x, eA1 = be2.y, eB0 = be2.x, eB1 = be2.y;
        #pragma unroll
        for (int i = 0; i < II; i++) {
            eA0 += vA[i] * we2[i].x; eA1 += vA[i] * we2[i].y;
            eB0 += vB[i] * we2[i].x; eB1 += vB[i] * we2[i].y;
        }
        float mfA = mrow[cA] ? 1.0f : 0.0f;
        float mfB = mrow[cB] ? 1.0f : 0.0f;
        float aA0 = fast_gelu(eA0) * mfA, aA1 = fast_gelu(eA1) * mfA;
        float aB0 = fast_gelu(eB0) * mfB, aB1 = fast_gelu(eB1) * mfB;
        float sA = aA0 + aA1, sB = aB0 + aB1;
        #pragma unroll
        for (int o = 32; o >= 1; o >>= 1) {
            sA += __shfl_xor(sA, o, 64); sB += __shfl_xor(sB, o, 64);
        }
        float muA = sA * (1.0f / 128.0f), muB = sB * (1.0f / 128.0f);
        float tA0 = aA0 - muA, tA1 = aA1 - muA;
        float tB0 = aB0 - muB, tB1 = aB1 - muB;
        float qA = tA0 * tA0 + tA1 * tA1, qB = tB0 * tB0 + tB1 * tB1;
        #pragma unroll
        for (int o = 32; o >= 1; o >>= 1) {
            qA += __shfl_xor(qA, o, 64); qB += __shfl_xor(qB, o, 64);
        }
        float rsA = rsqrtf(qA * (1.0f / 128.0f) + 1e-5f);
        float rsB = rsqrtf(qB * (1.0f / 128.0f) + 1e-5f);
        float xA0 = tA0 * rsA * g12.x + b12.x, xA1 = tA1 * rsA * g12.y + b12.y;
        float xB0 = tB0 * rsB * g12.x + b12.x, xB1 = tB1 * rsB * g12.y + b12.y;
        xs2[cA * 64 + lane] = __floats2half2_rn(xA0, xA1);
        xs2[cB * 64 + lane] = __floats2half2_rn(xB0, xB1);
        if (cA == r) xr2[lane] = make_float2(xA0, xA1);
        if (cB == r) xr2[lane] = make_float2(xB0, xB1);
    }
    __syncthreads();  // S1

    // ---- kq = x_r @ M (scaled by 1/sqrt(D))
    {
        const float* xrf = (const float*)xr2;
        const float2* M2 = (const float2*)Mws;
        float ax = 0.0f, ay = 0.0f;
        #pragma unroll 8
        for (int j = 0; j < 32; j++) {
            int a = (wave << 5) + j;
            float xv = xrf[a];
            float2 m2 = M2[a * 64 + lane];
            ax += xv * m2.x; ay += xv * m2.y;
        }
        pbuf2[(wave << 6) + lane] = make_float2(ax, ay);
    }
    __syncthreads();  // S2
    if (t < 64) {
        float2 p0 = pbuf2[t], p1 = pbuf2[64 + t], p2 = pbuf2[128 + t], p3 = pbuf2[192 + t];
        kq2[t] = make_float2((p0.x + p1.x + p2.x + p3.x) * 0.08838834764831845f,
                             (p0.y + p1.y + p2.y + p3.y) * 0.08838834764831845f);
    }
    __syncthreads();  // S3

    // ---- logits[c] = xs[c] . kq  (2 threads per c, staggered to dodge bank conflicts)
    {
        int c = t >> 1, p = t & 1;
        float acc = 0.0f;
        #pragma unroll 8
        for (int jj = 0; jj < 32; jj++) {
            int idx = (p << 5) + ((c + jj) & 31);
            float2 xf = __half22float2(xs2[c * 64 + idx]);
            float2 kv = kq2[idx];
            acc += xf.x * kv.x + xf.y * kv.y;
        }
        lp[p * TT + c] = acc;
    }
    __syncthreads();  // S4

    // ---- softmax (wave 0)
    if (wave == 0) {
        int c0 = lane, c1 = lane + 64;
        float l0 = lp[c0] + lp[TT + c0];
        float l1 = lp[c1] + lp[TT + c1];
        bool v0 = (mrow[c0] != 0) || (c0 == r);
        bool v1 = (mrow[c1] != 0) || (c1 == r);
        l0 = v0 ? l0 : -1e9f;
        l1 = v1 ? l1 : -1e9f;
        float mx = fmaxf(l0, l1);
        #pragma unroll
        for (int o = 32; o >= 1; o >>= 1) mx = fmaxf(mx, __shfl_xor(mx, o, 64));
        float e0 = __expf(l0 - mx), e1 = __expf(l1 - mx);
        float s = e0 + e1;
        #pragma unroll
        for (int o = 32; o >= 1; o >>= 1) s += __shfl_xor(s, o, 64);
        float inv = __fdividef(1.0f, s);
        wgt[c0] = e0 * inv; wgt[c1] = e1 * inv;
    }
    __syncthreads();  // S5

    // ---- s[d] = sum_c w_c * x_c[d]
    {
        float ax = 0.0f, ay = 0.0f;
        #pragma unroll 8
        for (int j = 0; j < 32; j++) {
            int c = (wave << 5) + j;
            float w = wgt[c];
            float2 xf = __half22float2(xs2[c * 64 + lane]);
            ax += w * xf.x; ay += w * xf.y;
        }
        pbuf2[(wave << 6) + lane] = make_float2(ax, ay);
    }
    __syncthreads();  // S6
    if (t < 64) {
        float2 p0 = pbuf2[t], p1 = pbuf2[64 + t], p2 = pbuf2[128 + t], p3 = pbuf2[192 + t];
        sv2[t] = make_float2(p0.x + p1.x + p2.x + p3.x, p0.y + p1.y + p2.y + p3.y);
    }
    __syncthreads();  // S7

    // ---- emb = s @ Wv
    {
        const float* svf = (const float*)sv2;
        const float2* Wv2 = (const float2*)Wv;
        float ax = 0.0f, ay = 0.0f;
        #pragma unroll 8
        for (int j = 0; j < 32; j++) {
            int e = (wave << 5) + j;
            float s = svf[e];
            float2 w2 = Wv2[e * 64 + lane];
            ax += s * w2.x; ay += s * w2.y;
        }
        pbuf2[(wave << 6) + lane] = make_float2(ax, ay);
    }
    __syncthreads();  // S8
    if (t < 64) {
        float2 p0 = pbuf2[t], p1 = pbuf2[64 + t], p2 = pbuf2[128 + t], p3 = pbuf2[192 + t];
        emb2[t] = make_float2(p0.x + p1.x + p2.x + p3.x, p0.y + p1.y + p2.y + p3.y);
    }
    __syncthreads();  // S9

    // ---- h_pre = emb @ Wo
    {
        const float* ef = (const float*)emb2;
        const float2* Wo2 = (const float2*)Wo;
        float ax = 0.0f, ay = 0.0f;
        #pragma unroll 8
        for (int j = 0; j < 32; j++) {
            int e = (wave << 5) + j;
            float s = ef[e];
            float2 w2 = Wo2[e * 64 + lane];
            ax += s * w2.x; ay += s * w2.y;
        }
        pbuf2[(wave << 6) + lane] = make_float2(ax, ay);
    }
    __syncthreads();  // S10

    // ---- LN2(gelu(h_pre + bo) + emb) * seq  (wave 0 only) + tail outputs
    if (wave == 0) {
        float2 p0 = pbuf2[lane], p1 = pbuf2[64 + lane], p2 = pbuf2[128 + lane], p3 = pbuf2[192 + lane];
        float2 bo2 = ((const float2*)bo)[lane];
        float2 em = emb2[lane];
        float h0 = fast_gelu(p0.x + p1.x + p2.x + p3.x + bo2.x);
        float h1 = fast_gelu(p0.y + p1.y + p2.y + p3.y + bo2.y);
        float z0 = h0 + em.x, z1 = h1 + em.y;
        float s = z0 + z1;
        #pragma unroll
        for (int o = 32; o >= 1; o >>= 1) s += __shfl_xor(s, o, 64);
        float mu = s * (1.0f / 128.0f);
        float u0 = z0 - mu, u1 = z1 - mu;
        float q = u0 * u0 + u1 * u1;
        #pragma unroll
        for (int o = 32; o >= 1; o >>= 1) q += __shfl_xor(q, o, 64);
        float rstd = rsqrtf(q * (1.0f / 128.0f) + 1e-5f);
        float2 g22 = ((const float2*)g2)[lane], b22 = ((const float2*)b2)[lane];
        float seqf = mrow[r] ? 1.0f : 0.0f;
        float o0 = (u0 * rstd * g22.x + b22.x) * seqf;
        float o1 = (u1 * rstd * g22.y + b22.y) * seqf;
        ((float2*)out)[rb * 64 + lane] = make_float2(o0, o1);
        if (lane == 0) {
            out[262144 + b * TT + r] = 1.0f - seqf;   // padding_mask = !real
            out[264192 + r * BB + b] = seqf;          // sequence_mask
            if (b == 0) out[266240 + r] = 1.0f;       // global_mask
        }
    }
}

extern "C" void kernel_launch(void* const* d_in, const int* in_sizes, int n_in,
                              void* d_out, int out_size, void* d_ws, size_t ws_size,
                              hipStream_t stream) {
    const float* vectors = (const float*)d_in[0];
    const int*   mask    = (const int*)d_in[1];
    const float* W_embed = (const float*)d_in[2];
    const float* b_embed = (const float*)d_in[3];
    const float* ln1_g   = (const float*)d_in[4];
    const float* ln1_b   = (const float*)d_in[5];
    const float* Wq      = (const float*)d_in[6];
    const float* Wk      = (const float*)d_in[7];
    const float* Wv      = (const float*)d_in[8];
    const float* W_out   = (const float*)d_in[9];
    const float* b_out   = (const float*)d_in[10];
    const float* ln2_g   = (const float*)d_in[11];
    const float* ln2_b   = (const float*)d_in[12];
    float* out = (float*)d_out;

    float* M = (float*)d_ws;   // 128*128 floats

    hipLaunchKernelGGL(k0_compute_M, dim3(DD), dim3(DD), 0, stream, Wq, Wk, M);
    hipLaunchKernelGGL(k_fused, dim3(TT * BB), dim3(256), 0, stream,
                       vectors, mask, W_embed, b_embed, ln1_g, ln1_b,
                       Wv, W_out, b_out, ln2_g, ln2_b, M, out);
}